// Round 3
// baseline (217.409 us; speedup 1.0000x reference)
//
#include <hip/hip_runtime.h>
#include <hip/hip_bf16.h>
#include <stdint.h>

using frag = __attribute__((ext_vector_type(8))) short;   // 8 bf16 in 4 VGPRs
using f4   = __attribute__((ext_vector_type(4))) float;   // 4 fp32 acc
using bf16 = __hip_bfloat16;

// B=4, T=1024, E=1024, H=16, Dk=64.  Global I/O fp32; compute bf16 MFMA.
static constexpr float WEPS = 1e-5f;
// p = exp(s*sc - 8) = exp2(s*(sc*log2e) - 8*log2e); sc = 0.125*w*w
static constexpr float SC2K  = 0.125f * 1.44269504f;   // 0.18033688
static constexpr float EBIAS = -8.0f * 1.44269504f;    // -11.5415603

#define AS1(p) ((const __attribute__((address_space(1))) void*)(p))
#define AS3(p) ((__attribute__((address_space(3))) void*)(p))

__device__ __forceinline__ void gl2lds16(const void* g, void* l) {
    __builtin_amdgcn_global_load_lds(AS1(g), AS3(l), 16, 0, 0);
}

__device__ inline uint4 pack8(float4 a, float4 b) {
    union { bf16 h[8]; uint4 u; } x;
    x.h[0] = __float2bfloat16(a.x); x.h[1] = __float2bfloat16(a.y);
    x.h[2] = __float2bfloat16(a.z); x.h[3] = __float2bfloat16(a.w);
    x.h[4] = __float2bfloat16(b.x); x.h[5] = __float2bfloat16(b.y);
    x.h[6] = __float2bfloat16(b.z); x.h[7] = __float2bfloat16(b.w);
    return x.u;
}

__device__ __forceinline__ uint2 pack4(float a, float b, float c, float d) {
    union { bf16 h[4]; uint2 u; } x;
    x.h[0] = __float2bfloat16(a); x.h[1] = __float2bfloat16(b);
    x.h[2] = __float2bfloat16(c); x.h[3] = __float2bfloat16(d);
    return x.u;
}

// key-position permutation within each 64-token group:
// pos(j*16+lr) = lr*4+j.  Applied to vhT columns AND P columns identically.
__device__ __forceinline__ int tperm(int t) {
    return (t & ~63) | (((t & 15) << 2) | ((t >> 4) & 3));
}

// ---------------------------------------------------------------------------
// Multi-segment fp32 -> bf16 convert into one contiguous bf16 region.
// ---------------------------------------------------------------------------
struct CvtArgs {
    const float* src[7];
    long long    bounds[8];
    long long    total;
};

__global__ __launch_bounds__(256) void cvt_kernel(CvtArgs a, bf16* __restrict__ dst)
{
    long long e = ((long long)blockIdx.x * 256 + threadIdx.x) * 8;
    if (e >= a.total) return;
    int s = 0;
    while (e >= a.bounds[s + 1]) s++;
    const float* src = a.src[s] + (e - a.bounds[s]);
    float4 f0 = ((const float4*)src)[0];
    float4 f1 = ((const float4*)src)[1];
    *(uint4*)(dst + e) = pack8(f0, f1);
}

// ---------------------------------------------------------------------------
// Batched GEMM, 128x128 tile, BK=32, DOUBLE-BUFFERED LDS (1 barrier/iter).
// r10 confirmed: this 2-buffer structure = 50us / 19% MfmaUtil; the r9
// 3-ring counted-vmcnt variant regressed to 70us (runtime ring index
// defeats LDS-DMA/ds_read alias disambiguation -> compiler drains vmcnt
// before the fragment reads).  At 3 blocks/CU the implicit inter-block
// overlap (m114) hides the syncthreads drain.
// XCD swizzle: big=(lid&7)*4+(lid>>6) (r8: FETCH 101->37MB, dur 63->49.5us).
// Out[m,n] = sum_k A[m,k]*W[n,k] + bias[n]
// mode 0: (B,H,T,Dk) bf16 | mode 2: (B,H,Dk,T) scatter (key-permuted)
// mode 3: fp32 row-major  | mode 4: swapped operands -> (B,H,Dk,T) key-permuted
// ---------------------------------------------------------------------------
struct GemmBatch {
    const void*  A[3];
    const void*  W[3];
    const float* bias[3];
    void*        Out[3];
    int          mode[3];
};

template<bool ABF, bool WBF>
__global__ __launch_bounds__(256) void gemm_batch(GemmBatch g)
{
    constexpr int K = 1024;
    __shared__ bf16 As[2][128 * 32];
    __shared__ bf16 Bs[2][128 * 32];

    const int z = blockIdx.z;
    const void*  Ap   = g.A[z];
    const void*  Wp   = g.W[z];
    const float* bias = g.bias[z];
    void*        OutP = g.Out[z];
    const int    mode = g.mode[z];

    const int tid = threadIdx.x;
    const int lid = blockIdx.x + 8 * blockIdx.y;       // 0..255
    const int big   = (lid & 7) * 4 + (lid >> 6);      // 0..31 (XCD-grouped)
    const int small = (lid >> 3) & 7;                  // 0..7
    int m0, n0;
    if (mode == 4) { m0 = small * 128; n0 = big * 128; }
    else           { m0 = big * 128;   n0 = small * 128; }

    const int lane = tid & 63;
    const int wave = tid >> 6;
    const int wm   = (wave >> 1) * 64;
    const int wn   = (wave & 1) * 64;
    const int lr   = lane & 15;
    const int q    = lane >> 4;

    const int sr = tid >> 1;
    const int sc = (tid & 1) * 16;

    const int c0 = wave * 128 + lane;
    const int c1 = c0 + 64;
    const int r0 = c0 >> 2, col0 = (c0 & 3) * 8;
    const int r1 = c1 >> 2, col1 = (c1 & 3) * 8;

    auto stage = [&](int k0, int pb) {
        if (WBF) {
            const bf16* W = (const bf16*)Wp;
            gl2lds16(&W[(size_t)(n0 + r0) * K + k0 + col0], &Bs[pb][wave * 1024]);
            gl2lds16(&W[(size_t)(n0 + r1) * K + k0 + col1], &Bs[pb][wave * 1024 + 512]);
        } else {
            const float* W = (const float*)Wp;
            const float* src = &W[(size_t)(n0 + sr) * K + k0 + sc];
            float4 f0 = ((const float4*)src)[0];
            float4 f1 = ((const float4*)src)[1];
            float4 f2 = ((const float4*)src)[2];
            float4 f3 = ((const float4*)src)[3];
            *(uint4*)(&Bs[pb][sr * 32 + sc])     = pack8(f0, f1);
            *(uint4*)(&Bs[pb][sr * 32 + sc + 8]) = pack8(f2, f3);
        }
        if (ABF) {
            const bf16* A = (const bf16*)Ap;
            gl2lds16(&A[(size_t)(m0 + r0) * K + k0 + col0], &As[pb][wave * 1024]);
            gl2lds16(&A[(size_t)(m0 + r1) * K + k0 + col1], &As[pb][wave * 1024 + 512]);
        } else {
            const float* A = (const float*)Ap;
            const float* src = &A[(size_t)(m0 + sr) * K + k0 + sc];
            float4 f0 = ((const float4*)src)[0];
            float4 f1 = ((const float4*)src)[1];
            float4 f2 = ((const float4*)src)[2];
            float4 f3 = ((const float4*)src)[3];
            *(uint4*)(&As[pb][sr * 32 + sc])     = pack8(f0, f1);
            *(uint4*)(&As[pb][sr * 32 + sc + 8]) = pack8(f2, f3);
        }
    };

    f4 acc[4][4];
    #pragma unroll
    for (int i = 0; i < 4; i++)
        #pragma unroll
        for (int j = 0; j < 4; j++) acc[i][j] = f4{0.f, 0.f, 0.f, 0.f};

    stage(0, 0);
    __syncthreads();

    for (int kt = 0; kt < 32; kt++) {
        const int cb = kt & 1;
        if (kt < 31) stage((kt + 1) * 32, cb ^ 1);

        frag af[4], bfr[4];
        #pragma unroll
        for (int i = 0; i < 4; i++)
            af[i] = *(const frag*)(&As[cb][(wm + i * 16 + lr) * 32 + q * 8]);
        #pragma unroll
        for (int j = 0; j < 4; j++)
            bfr[j] = *(const frag*)(&Bs[cb][(wn + j * 16 + lr) * 32 + q * 8]);
        #pragma unroll
        for (int i = 0; i < 4; i++)
            #pragma unroll
            for (int j = 0; j < 4; j++)
                acc[i][j] = __builtin_amdgcn_mfma_f32_16x16x32_bf16(af[i], bfr[j], acc[i][j], 0, 0, 0);
        __syncthreads();
    }

    // epilogue: D row = quad*4+reg, col = lane&15
    if (mode == 4) {
        const int bbt   = (n0 + wn) >> 10;
        const int tbase = (n0 + wn) & 1023;        // 64-aligned
        bf16* O = (bf16*)OutP;
        #pragma unroll
        for (int i = 0; i < 4; i++) {
            int row0 = m0 + wm + i * 16 + q * 4;
            #pragma unroll
            for (int r = 0; r < 4; r++) {
                int f = row0 + r;                  // feature index
                int h = f >> 6, d = f & 63;
                float bv = bias[f];
                size_t idx = ((((size_t)bbt * 16 + h) * 64 + d) << 10) + tbase + lr * 4;
                *(uint2*)(&O[idx]) = pack4(acc[i][0][r] + bv, acc[i][1][r] + bv,
                                           acc[i][2][r] + bv, acc[i][3][r] + bv);
            }
        }
    } else {
        #pragma unroll
        for (int i = 0; i < 4; i++) {
            int row0 = m0 + wm + i * 16 + q * 4;
            #pragma unroll
            for (int j = 0; j < 4; j++) {
                int col = n0 + wn + j * 16 + lr;
                float bv = bias[col];
                #pragma unroll
                for (int r = 0; r < 4; r++) {
                    float val = acc[i][j][r] + bv;
                    int mrow = row0 + r;
                    if (mode == 3) {
                        ((float*)OutP)[(size_t)mrow * 1024 + col] = val;
                    } else {
                        int bb = mrow >> 10, t = mrow & 1023;
                        int h  = col >> 6,   d = col & 63;
                        size_t idx;
                        if (mode == 2)
                            idx = ((((size_t)bb * 16 + h) * 64 + d) << 10) + tperm(t);
                        else
                            idx = ((((size_t)bb * 16 + h) << 10) + t) * 64 + d;
                        ((bf16*)OutP)[idx] = __float2bfloat16(val);
                    }
                }
            }
        }
    }
}

// ---------------------------------------------------------------------------
// Output GEMM: 64(M) x 128(N) tiles, BK=64, 3-DEEP LDS RING + counted vmcnt.
// r10: kept unchanged this round (r1/r2 totals were too noisy to attribute;
// per-dispatch data never indicted it).  6 gl2lds/thread/tile -> vmcnt(6).
// LDS 72KB -> 2 blocks/CU, same as grid-implied 2.  XCD swizzle on block ids.
// ---------------------------------------------------------------------------
template<bool WBF>
__global__ __launch_bounds__(256) void gemm_out(const bf16* __restrict__ A,
                                                const void* __restrict__ Wp,
                                                const float* __restrict__ bias,
                                                float* __restrict__ Out)
{
    constexpr int K = 1024;
    __shared__ bf16 As[3][64 * 64];     // 24 KB
    __shared__ bf16 Bs[3][128 * 64];    // 48 KB

    const int tid = threadIdx.x;
    const int lid = blockIdx.x + 8 * blockIdx.y;       // 0..511
    const int mt  = (lid & 7) * 8 + (lid >> 6);        // 0..63 (XCD-grouped)
    const int nt  = (lid >> 3) & 7;                    // 0..7
    const int n0  = nt * 128;
    const int m0  = mt * 64;
    const int lane = tid & 63;
    const int wave = tid >> 6;
    const int wm   = (wave >> 1) * 32;
    const int wn   = (wave & 1) * 64;
    const int lr   = lane & 15;
    const int q    = lane >> 4;

    const int sr = tid >> 1;
    const int sc = (tid & 1) * 32;

    // B tile 128x64 = 1024 chunks of 16B (8 chunks/row), 4 per thread
    int rb[4], cb4[4];
    #pragma unroll
    for (int gg = 0; gg < 4; gg++) {
        int D = wave * 256 + gg * 64 + lane;
        rb[gg]  = D >> 3;
        cb4[gg] = (D & 7) * 8;
    }
    // A tile 64x64 = 512 chunks, 2 per thread
    int ra[2], ca4[2];
    #pragma unroll
    for (int gg = 0; gg < 2; gg++) {
        int D = wave * 128 + gg * 64 + lane;
        ra[gg]  = D >> 3;
        ca4[gg] = (D & 7) * 8;
    }

    auto stage = [&](int k0, int pb) {
        if (WBF) {
            const bf16* W = (const bf16*)Wp;
            #pragma unroll
            for (int gg = 0; gg < 4; gg++)
                gl2lds16(&W[(size_t)(n0 + rb[gg]) * K + k0 + cb4[gg]],
                         &Bs[pb][(wave * 256 + gg * 64) * 8]);
        } else {
            const float* W = (const float*)Wp;
            const float* src = &W[(size_t)(n0 + sr) * K + k0 + sc];
            #pragma unroll
            for (int c = 0; c < 4; c++) {
                float4 f0 = ((const float4*)src)[2 * c];
                float4 f1 = ((const float4*)src)[2 * c + 1];
                *(uint4*)(&Bs[pb][sr * 64 + sc + c * 8]) = pack8(f0, f1);
            }
        }
        #pragma unroll
        for (int gg = 0; gg < 2; gg++)
            gl2lds16(&A[(size_t)(m0 + ra[gg]) * K + k0 + ca4[gg]],
                     &As[pb][(wave * 128 + gg * 64) * 8]);
    };

    f4 acc[2][4];
    #pragma unroll
    for (int i = 0; i < 2; i++)
        #pragma unroll
        for (int j = 0; j < 4; j++) acc[i][j] = f4{0.f, 0.f, 0.f, 0.f};

    stage(0, 0);
    stage(64, 1);
    if (WBF) {
        asm volatile("s_waitcnt vmcnt(6)" ::: "memory");
        __builtin_amdgcn_s_barrier();
    } else {
        __syncthreads();
    }

    int cb = 0;
    for (int kt = 0; kt < 16; kt++) {
        if (kt < 14) {
            int sb = cb + 2; if (sb >= 3) sb -= 3;
            stage((kt + 2) * 64, sb);
        }

        #pragma unroll
        for (int kk = 0; kk < 2; kk++) {
            frag af[2], bfr[4];
            #pragma unroll
            for (int i = 0; i < 2; i++)
                af[i] = *(const frag*)(&As[cb][(wm + i * 16 + lr) * 64 + kk * 32 + q * 8]);
            #pragma unroll
            for (int j = 0; j < 4; j++)
                bfr[j] = *(const frag*)(&Bs[cb][(wn + j * 16 + lr) * 64 + kk * 32 + q * 8]);
            #pragma unroll
            for (int i = 0; i < 2; i++)
                #pragma unroll
                for (int j = 0; j < 4; j++)
                    acc[i][j] = __builtin_amdgcn_mfma_f32_16x16x32_bf16(af[i], bfr[j], acc[i][j], 0, 0, 0);
        }

        if (kt < 15) {
            if (WBF) {
                if (kt < 14) asm volatile("s_waitcnt vmcnt(6)" ::: "memory");
                else         asm volatile("s_waitcnt vmcnt(0)" ::: "memory");
                __builtin_amdgcn_s_barrier();
            } else {
                __syncthreads();
            }
        }
        cb = cb + 1; if (cb == 3) cb = 0;
    }

    #pragma unroll
    for (int i = 0; i < 2; i++) {
        int row0 = m0 + wm + i * 16 + q * 4;
        #pragma unroll
        for (int j = 0; j < 4; j++) {
            int col = n0 + wn + j * 16 + lr;
            float bv = bias[col];
            #pragma unroll
            for (int r = 0; r < 4; r++)
                Out[(size_t)(row0 + r) * 1024 + col] = acc[i][j][r] + bv;
        }
    }
}

// ---------------------------------------------------------------------------
// Flash attention, r11 RESTRUCTURE: 16 q-rows/wave (64/block), grid (64 bh,
// 16 qtiles) = 1024 blocks.  Rationale: old 128-row blocks gave a 512-block
// grid = 2 blocks/CU = 2 waves/SIMD (grid-capped, launch_bounds(256,3)
// couldn't be filled) -- too little TLP to hide the per-tile serial chain
// (QK mfma -> exp2 -> P write -> P read -> PV mfma -> barrier).  64-row
// blocks shrink LDS 50->41KB (K/V dbuf 32KB + Plds 4x16x72x2B) so THREE
// blocks/CU fit = 12 waves/CU (+50% TLP).  K/V staged 16x per bh instead of
// 8x, but all 16 qtile-blocks of a bh land on the same XCD (bh fastest-
// varying, 64%8==0) -> extra reads are L2-local.  Per-wave state halves
// (no rf loop) so VGPR well under the (256,3) cap.
// Fixed-shift softmax (exact), mask folded into exp bias.  P strip padded
// to 72.  P stored key-permuted (pos=lr*4+j); vhT carries the same perm.
// Double-buffered K/V via glds, 1 barrier/tile.
// ---------------------------------------------------------------------------
__global__ __launch_bounds__(256, 3) void attn_kernel(const bf16* __restrict__ qh,
                                                      const bf16* __restrict__ kh,
                                                      const bf16* __restrict__ vhT,
                                                      const float* __restrict__ wts,
                                                      bf16* __restrict__ att)
{
    constexpr int LDP = 72;
    __shared__ bf16 Ks[2][64 * 64];
    __shared__ bf16 Vs[2][64 * 64];
    __shared__ bf16 Plds[4][16 * LDP];

    const int tid  = threadIdx.x;
    const int lane = tid & 63;
    const int wave = tid >> 6;
    const int lr   = lane & 15;
    const int q    = lane >> 4;
    const int bh   = blockIdx.x;               // 0..63
    const int bb   = bh >> 4;
    const int h    = bh & 15;
    const int q0w  = blockIdx.y * 64 + wave * 16;
    const size_t base = (size_t)bh * 1024 * 64;

    const int cA = wave * 128 + lane;
    const int cB = cA + 64;
    const int rowA = cA >> 3, gA = ((cA & 7) ^ (rowA & 7)) * 8;
    const int rowB = cB >> 3, gB = ((cB & 7) ^ (rowB & 7)) * 8;

    frag aq[2];
    #pragma unroll
    for (int ks = 0; ks < 2; ks++)
        aq[ks] = *(const frag*)(&qh[base + (size_t)(q0w + lr) * 64 + ks * 32 + q * 8]);

    float rs[4];
    f4 o[4];
    #pragma unroll
    for (int j = 0; j < 4; j++) {
        o[j] = f4{0.f, 0.f, 0.f, 0.f};
        rs[j] = 0.f;
    }

    gl2lds16(&kh [base + (size_t)rowA * 64 + gA],   &Ks[0][wave * 1024]);
    gl2lds16(&kh [base + (size_t)rowB * 64 + gB],   &Ks[0][wave * 1024 + 512]);
    gl2lds16(&vhT[base + (size_t)rowA * 1024 + gA], &Vs[0][wave * 1024]);
    gl2lds16(&vhT[base + (size_t)rowB * 1024 + gB], &Vs[0][wave * 1024 + 512]);
    __syncthreads();

    for (int t = 0; t < 16; t++) {
        const int k0  = t * 64;
        const int buf = t & 1;
        if (t < 15) {
            int kn = k0 + 64;
            gl2lds16(&kh [base + (size_t)(kn + rowA) * 64 + gA],  &Ks[buf ^ 1][wave * 1024]);
            gl2lds16(&kh [base + (size_t)(kn + rowB) * 64 + gB],  &Ks[buf ^ 1][wave * 1024 + 512]);
            gl2lds16(&vhT[base + (size_t)rowA * 1024 + kn + gA], &Vs[buf ^ 1][wave * 1024]);
            gl2lds16(&vhT[base + (size_t)rowB * 1024 + kn + gB], &Vs[buf ^ 1][wave * 1024 + 512]);
        }

        // per-key scale; mask folded into bias (exp2(-1e30)=0)
        float sc2[4], eb[4];
        #pragma unroll
        for (int j = 0; j < 4; j++) {
            float w = wts[bb * 1024 + k0 + j * 16 + lr];
            sc2[j] = SC2K * w * w;
            eb[j]  = (w < WEPS) ? -1e30f : EBIAS;
        }

        // K fragments
        frag kb[4][2];
        #pragma unroll
        for (int j = 0; j < 4; j++) {
            int rowj = j * 16 + lr;
            kb[j][0] = *(const frag*)(&Ks[buf][rowj * 64 + (((q    ) ^ (rowj & 7)) * 8)]);
            kb[j][1] = *(const frag*)(&Ks[buf][rowj * 64 + (((q + 4) ^ (rowj & 7)) * 8)]);
        }

        // S = Q K^T  (16 q-rows)
        f4 s[4];
        #pragma unroll
        for (int j = 0; j < 4; j++) {
            f4 z = f4{0.f, 0.f, 0.f, 0.f};
            s[j] = __builtin_amdgcn_mfma_f32_16x16x32_bf16(aq[0], kb[j][0], z, 0, 0, 0);
            s[j] = __builtin_amdgcn_mfma_f32_16x16x32_bf16(aq[1], kb[j][1], s[j], 0, 0, 0);
        }
        float p[4][4];
        #pragma unroll
        for (int j = 0; j < 4; j++)
            #pragma unroll
            for (int r = 0; r < 4; r++) {
                p[j][r] = __builtin_amdgcn_exp2f(fmaf(s[j][r], sc2[j], eb[j]));
                rs[r] += p[j][r];
            }
        #pragma unroll
        for (int r = 0; r < 4; r++)
            *(uint2*)(&Plds[wave][(q * 4 + r) * LDP + lr * 4]) =
                pack4(p[0][r], p[1][r], p[2][r], p[3][r]);

        // V fragments
        frag vb[4][2];
        #pragma unroll
        for (int j = 0; j < 4; j++) {
            int rowj = j * 16 + lr;
            vb[j][0] = *(const frag*)(&Vs[buf][rowj * 64 + (((q    ) ^ (rowj & 7)) * 8)]);
            vb[j][1] = *(const frag*)(&Vs[buf][rowj * 64 + (((q + 4) ^ (rowj & 7)) * 8)]);
        }

        frag ap0 = *(const frag*)(&Plds[wave][lr * LDP + q * 8]);
        frag ap1 = *(const frag*)(&Plds[wave][lr * LDP + 32 + q * 8]);
        #pragma unroll
        for (int j = 0; j < 4; j++) {
            o[j] = __builtin_amdgcn_mfma_f32_16x16x32_bf16(ap0, vb[j][0], o[j], 0, 0, 0);
            o[j] = __builtin_amdgcn_mfma_f32_16x16x32_bf16(ap1, vb[j][1], o[j], 0, 0, 0);
        }
        __syncthreads();
    }

    #pragma unroll
    for (int off = 1; off < 16; off <<= 1)
        #pragma unroll
        for (int r = 0; r < 4; r++)
            rs[r] += __shfl_xor(rs[r], off, 64);

    float inv[4];
    #pragma unroll
    for (int r = 0; r < 4; r++) inv[r] = 1.0f / rs[r];
    const int t0 = q0w + q * 4;
    #pragma unroll
    for (int j = 0; j < 4; j++) {
        int d = h * 64 + j * 16 + lr;
        #pragma unroll
        for (int r = 0; r < 4; r++)
            att[((size_t)bb * 1024 + t0 + r) * 1024 + d] =
                __float2bfloat16(o[j][r] * inv[r]);
    }
}

// ---------------------------------------------------------------------------
extern "C" void kernel_launch(void* const* d_in, const int* in_sizes, int n_in,
                              void* d_out, int out_size, void* d_ws, size_t ws_size,
                              hipStream_t stream)
{
    const float* q   = (const float*)d_in[0];
    const float* k   = (const float*)d_in[1];
    const float* v   = (const float*)d_in[2];
    const float* wts = (const float*)d_in[3];
    const float* Wq  = (const float*)d_in[4];
    const float* bq  = (const float*)d_in[5];
    const float* Wk  = (const float*)d_in[6];
    const float* bk  = (const float*)d_in[7];
    const float* Wv  = (const float*)d_in[8];
    const float* bv  = (const float*)d_in[9];
    const float* Wo  = (const float*)d_in[10];
    const float* bo  = (const float*)d_in[11];
    float* out = (float*)d_out;

    const long long Mi = 1024 * 1024;
    bf16* qh  = (bf16*)d_ws;
    bf16* kh  = qh  + 4 * Mi;
    bf16* vhT = kh  + 4 * Mi;
    bf16* att = vhT + 4 * Mi;
    bf16* cvt = att + 4 * Mi;
    const size_t base_bytes = (size_t)32 * Mi;

    dim3 blk(256);

    if (ws_size >= base_bytes + (size_t)32 * Mi) {
        // FULL: pre-convert q,k,v + all weights to bf16
        CvtArgs ca{};
        ca.src[0] = q;  ca.src[1] = k;  ca.src[2] = v;
        ca.src[3] = Wq; ca.src[4] = Wk; ca.src[5] = Wv; ca.src[6] = Wo;
        long long bnd[8] = {0, 4*Mi, 8*Mi, 12*Mi, 13*Mi, 14*Mi, 15*Mi, 16*Mi};
        for (int i = 0; i < 8; i++) ca.bounds[i] = bnd[i];
        ca.total = 16 * Mi;
        cvt_kernel<<<8192, blk, 0, stream>>>(ca, cvt);

        GemmBatch gq{};
        gq.A[0] = cvt;          gq.A[1] = cvt + 4*Mi;   gq.A[2] = cvt + 14*Mi; // z2: A=Wv (swapped)
        gq.W[0] = cvt + 12*Mi;  gq.W[1] = cvt + 13*Mi;  gq.W[2] = cvt + 8*Mi;  // z2: W=v
        gq.bias[0] = bq; gq.bias[1] = bk; gq.bias[2] = bv;
        gq.Out[0] = qh;  gq.Out[1] = kh;  gq.Out[2] = vhT;
        gq.mode[0] = 0;  gq.mode[1] = 0;  gq.mode[2] = 4;
        gemm_batch<true, true><<<dim3(8, 32, 3), blk, 0, stream>>>(gq);

        attn_kernel<<<dim3(64, 16), blk, 0, stream>>>(qh, kh, vhT, wts, att);

        gemm_out<true><<<dim3(8, 64), blk, 0, stream>>>(att, cvt + 15*Mi, bo, out);
    } else if (ws_size >= base_bytes + (size_t)8 * Mi) {
        // HYBRID: pre-convert weights only
        CvtArgs ca{};
        ca.src[0] = Wq; ca.src[1] = Wk; ca.src[2] = Wv; ca.src[3] = Wo;
        long long bnd[8] = {0, 1*Mi, 2*Mi, 3*Mi, 4*Mi, 4*Mi, 4*Mi, 4*Mi};
        for (int i = 0; i < 8; i++) ca.bounds[i] = bnd[i];
        ca.total = 4 * Mi;
        cvt_kernel<<<2048, blk, 0, stream>>>(ca, cvt);

        GemmBatch gq{};
        gq.A[0] = q; gq.A[1] = k; gq.A[2] = v;
        gq.W[0] = cvt; gq.W[1] = cvt + 1*Mi; gq.W[2] = cvt + 2*Mi;
        gq.bias[0] = bq; gq.bias[1] = bk; gq.bias[2] = bv;
        gq.Out[0] = qh;  gq.Out[1] = kh;  gq.Out[2] = vhT;
        gq.mode[0] = 0;  gq.mode[1] = 0;  gq.mode[2] = 2;
        gemm_batch<false, true><<<dim3(8, 32, 3), blk, 0, stream>>>(gq);

        attn_kernel<<<dim3(64, 16), blk, 0, stream>>>(qh, kh, vhT, wts, att);

        gemm_out<true><<<dim3(8, 64), blk, 0, stream>>>(att, cvt + 3*Mi, bo, out);
    } else {
        // FALLBACK: no conversions
        GemmBatch gq{};
        gq.A[0] = q; gq.A[1] = k; gq.A[2] = v;
        gq.W[0] = Wq; gq.W[1] = Wk; gq.W[2] = Wv;
        gq.bias[0] = bq; gq.bias[1] = bk; gq.bias[2] = bv;
        gq.Out[0] = qh;  gq.Out[1] = kh;  gq.Out[2] = vhT;
        gq.mode[0] = 0;  gq.mode[1] = 0;  gq.mode[2] = 2;
        gemm_batch<false, false><<<dim3(8, 32, 3), blk, 0, stream>>>(gq);

        attn_kernel<<<dim3(64, 16), blk, 0, stream>>>(qh, kh, vhT, wts, att);

        gemm_out<false><<<dim3(8, 64), blk, 0, stream>>>(att, Wo, bo, out);
    }
}

// Round 4
// 206.797 us; speedup vs baseline: 1.0513x; 1.0513x over previous
//
#include <hip/hip_runtime.h>
#include <hip/hip_bf16.h>
#include <stdint.h>

using frag = __attribute__((ext_vector_type(8))) short;   // 8 bf16 in 4 VGPRs
using f4   = __attribute__((ext_vector_type(4))) float;   // 4 fp32 acc
using bf16 = __hip_bfloat16;

// B=4, T=1024, E=1024, H=16, Dk=64.  Global I/O fp32; compute bf16 MFMA.
static constexpr float WEPS = 1e-5f;
// p = exp(s*sc - 8) = exp2(s*(sc*log2e) - 8*log2e); sc = 0.125*w*w
static constexpr float SC2K  = 0.125f * 1.44269504f;   // 0.18033688
static constexpr float EBIAS = -8.0f * 1.44269504f;    // -11.5415603

#define AS1(p) ((const __attribute__((address_space(1))) void*)(p))
#define AS3(p) ((__attribute__((address_space(3))) void*)(p))

__device__ __forceinline__ void gl2lds16(const void* g, void* l) {
    __builtin_amdgcn_global_load_lds(AS1(g), AS3(l), 16, 0, 0);
}

__device__ inline uint4 pack8(float4 a, float4 b) {
    union { bf16 h[8]; uint4 u; } x;
    x.h[0] = __float2bfloat16(a.x); x.h[1] = __float2bfloat16(a.y);
    x.h[2] = __float2bfloat16(a.z); x.h[3] = __float2bfloat16(a.w);
    x.h[4] = __float2bfloat16(b.x); x.h[5] = __float2bfloat16(b.y);
    x.h[6] = __float2bfloat16(b.z); x.h[7] = __float2bfloat16(b.w);
    return x.u;
}

__device__ __forceinline__ uint2 pack4(float a, float b, float c, float d) {
    union { bf16 h[4]; uint2 u; } x;
    x.h[0] = __float2bfloat16(a); x.h[1] = __float2bfloat16(b);
    x.h[2] = __float2bfloat16(c); x.h[3] = __float2bfloat16(d);
    return x.u;
}

// key-position permutation within each 64-token group:
// pos(j*16+lr) = lr*4+j.  Applied to vhT columns AND P columns identically.
__device__ __forceinline__ int tperm(int t) {
    return (t & ~63) | (((t & 15) << 2) | ((t >> 4) & 3));
}

// ---------------------------------------------------------------------------
// Multi-segment fp32 -> bf16 convert into one contiguous bf16 region.
// ---------------------------------------------------------------------------
struct CvtArgs {
    const float* src[7];
    long long    bounds[8];
    long long    total;
};

__global__ __launch_bounds__(256) void cvt_kernel(CvtArgs a, bf16* __restrict__ dst)
{
    long long e = ((long long)blockIdx.x * 256 + threadIdx.x) * 8;
    if (e >= a.total) return;
    int s = 0;
    while (e >= a.bounds[s + 1]) s++;
    const float* src = a.src[s] + (e - a.bounds[s]);
    float4 f0 = ((const float4*)src)[0];
    float4 f1 = ((const float4*)src)[1];
    *(uint4*)(dst + e) = pack8(f0, f1);
}

// ---------------------------------------------------------------------------
// Batched GEMM, 128x128 tile, BK=32.
// r12 EXPERIMENT: depth-2 pipeline with STATICALLY-INDEXED 3-buffer LDS.
// r9's runtime-ring version regressed 50->70us; theory: runtime ring index
// defeats LDS-DMA/ds_read alias disambiguation -> compiler inserts its own
// vmcnt drain before the fragment reads.  Here the 3 buffers are six
// distinct __shared__ arrays and the loop is 3x-unrolled, so every stage
// target / read source is a compile-time-distinct object (trivial no-alias).
// Ledger (tile t -> buf t%3): prologue stages t0,t1 + vmcnt(4)+bar (t1 in
// flight).  Step s: stage(t_{s+2} -> buf[(s+2)%3], write-safe: last read in
// step s-1, separated by its barrier); compute(t_s); vmcnt(4)+bar (retire
// t_{s+1}, keep t_{s+2} in flight).  Never drains to 0 until the 2-tile
// tail.  1 barrier/tile, same as the syncthreads baseline, minus the drain.
// Counted path only when all staging is gl2lds (ABF&&WBF = FULL mode);
// fp32-staged modes use __syncthreads (ds_write needs lgkm drain).
// XCD swizzle: big=(lid&7)*4+(lid>>6) (r8: FETCH 101->37MB).
// Out[m,n] = sum_k A[m,k]*W[n,k] + bias[n]
// mode 0: (B,H,T,Dk) bf16 | mode 2: (B,H,Dk,T) scatter (key-permuted)
// mode 3: fp32 row-major  | mode 4: swapped operands -> (B,H,Dk,T) key-permuted
// ---------------------------------------------------------------------------
struct GemmBatch {
    const void*  A[3];
    const void*  W[3];
    const float* bias[3];
    void*        Out[3];
    int          mode[3];
};

template<bool ABF, bool WBF>
__global__ __launch_bounds__(256) void gemm_batch(GemmBatch g)
{
    constexpr int K = 1024;
    __shared__ bf16 As0[128 * 32], As1[128 * 32], As2[128 * 32];
    __shared__ bf16 Bs0[128 * 32], Bs1[128 * 32], Bs2[128 * 32];

    const int z = blockIdx.z;
    const void*  Ap   = g.A[z];
    const void*  Wp   = g.W[z];
    const float* bias = g.bias[z];
    void*        OutP = g.Out[z];
    const int    mode = g.mode[z];

    const int tid = threadIdx.x;
    const int lid = blockIdx.x + 8 * blockIdx.y;       // 0..255
    const int big   = (lid & 7) * 4 + (lid >> 6);      // 0..31 (XCD-grouped)
    const int small = (lid >> 3) & 7;                  // 0..7
    int m0, n0;
    if (mode == 4) { m0 = small * 128; n0 = big * 128; }
    else           { m0 = big * 128;   n0 = small * 128; }

    const int lane = tid & 63;
    const int wave = tid >> 6;
    const int wm   = (wave >> 1) * 64;
    const int wn   = (wave & 1) * 64;
    const int lr   = lane & 15;
    const int q    = lane >> 4;

    const int sr = tid >> 1;
    const int sc = (tid & 1) * 16;

    const int c0 = wave * 128 + lane;
    const int c1 = c0 + 64;
    const int r0 = c0 >> 2, col0 = (c0 & 3) * 8;
    const int r1 = c1 >> 2, col1 = (c1 & 3) * 8;

    auto stage = [&](int k0, bf16* Asd, bf16* Bsd) {
        if (WBF) {
            const bf16* W = (const bf16*)Wp;
            gl2lds16(&W[(size_t)(n0 + r0) * K + k0 + col0], &Bsd[wave * 1024]);
            gl2lds16(&W[(size_t)(n0 + r1) * K + k0 + col1], &Bsd[wave * 1024 + 512]);
        } else {
            const float* W = (const float*)Wp;
            const float* src = &W[(size_t)(n0 + sr) * K + k0 + sc];
            float4 f0 = ((const float4*)src)[0];
            float4 f1 = ((const float4*)src)[1];
            float4 f2 = ((const float4*)src)[2];
            float4 f3 = ((const float4*)src)[3];
            *(uint4*)(&Bsd[sr * 32 + sc])     = pack8(f0, f1);
            *(uint4*)(&Bsd[sr * 32 + sc + 8]) = pack8(f2, f3);
        }
        if (ABF) {
            const bf16* A = (const bf16*)Ap;
            gl2lds16(&A[(size_t)(m0 + r0) * K + k0 + col0], &Asd[wave * 1024]);
            gl2lds16(&A[(size_t)(m0 + r1) * K + k0 + col1], &Asd[wave * 1024 + 512]);
        } else {
            const float* A = (const float*)Ap;
            const float* src = &A[(size_t)(m0 + sr) * K + k0 + sc];
            float4 f0 = ((const float4*)src)[0];
            float4 f1 = ((const float4*)src)[1];
            float4 f2 = ((const float4*)src)[2];
            float4 f3 = ((const float4*)src)[3];
            *(uint4*)(&Asd[sr * 32 + sc])     = pack8(f0, f1);
            *(uint4*)(&Asd[sr * 32 + sc + 8]) = pack8(f2, f3);
        }
    };

    f4 acc[4][4];
    #pragma unroll
    for (int i = 0; i < 4; i++)
        #pragma unroll
        for (int j = 0; j < 4; j++) acc[i][j] = f4{0.f, 0.f, 0.f, 0.f};

    auto compute = [&](const bf16* Asp, const bf16* Bsp) {
        frag af[4], bfr[4];
        #pragma unroll
        for (int i = 0; i < 4; i++)
            af[i] = *(const frag*)(&Asp[(wm + i * 16 + lr) * 32 + q * 8]);
        #pragma unroll
        for (int j = 0; j < 4; j++)
            bfr[j] = *(const frag*)(&Bsp[(wn + j * 16 + lr) * 32 + q * 8]);
        #pragma unroll
        for (int i = 0; i < 4; i++)
            #pragma unroll
            for (int j = 0; j < 4; j++)
                acc[i][j] = __builtin_amdgcn_mfma_f32_16x16x32_bf16(af[i], bfr[j], acc[i][j], 0, 0, 0);
    };

    if (ABF && WBF) {
        // counted-vmcnt path: all staging is async DMA
        stage(0,  As0, Bs0);
        stage(32, As1, Bs1);
        asm volatile("s_waitcnt vmcnt(4)" ::: "memory");   // t0 done, t1 in flight
        __builtin_amdgcn_s_barrier();

        for (int m = 0; m < 10; m++) {
            const int kb = m * 96;                 // tile 3m at k0 = kb
            stage(kb + 64, As2, Bs2);              // t_{3m+2}
            compute(As0, Bs0);                     // t_{3m}
            asm volatile("s_waitcnt vmcnt(4)" ::: "memory");
            __builtin_amdgcn_s_barrier();

            stage(kb + 96, As0, Bs0);              // t_{3m+3}
            compute(As1, Bs1);                     // t_{3m+1}
            asm volatile("s_waitcnt vmcnt(4)" ::: "memory");
            __builtin_amdgcn_s_barrier();

            stage(kb + 128, As1, Bs1);             // t_{3m+4}
            compute(As2, Bs2);                     // t_{3m+2}
            asm volatile("s_waitcnt vmcnt(4)" ::: "memory");
            __builtin_amdgcn_s_barrier();
        }
        // tail: tiles 30 (b0), 31 (b1); t30 already retired by last vmcnt(4)
        compute(As0, Bs0);                         // t30
        asm volatile("s_waitcnt vmcnt(0)" ::: "memory");
        __builtin_amdgcn_s_barrier();
        compute(As1, Bs1);                         // t31
    } else {
        // ds_write staging path: full syncthreads per step
        stage(0,  As0, Bs0);
        stage(32, As1, Bs1);
        __syncthreads();
        for (int m = 0; m < 10; m++) {
            const int kb = m * 96;
            stage(kb + 64, As2, Bs2);
            compute(As0, Bs0);
            __syncthreads();
            stage(kb + 96, As0, Bs0);
            compute(As1, Bs1);
            __syncthreads();
            stage(kb + 128, As1, Bs1);
            compute(As2, Bs2);
            __syncthreads();
        }
        compute(As0, Bs0);
        __syncthreads();
        compute(As1, Bs1);
    }

    // epilogue: D row = quad*4+reg, col = lane&15
    if (mode == 4) {
        const int bbt   = (n0 + wn) >> 10;
        const int tbase = (n0 + wn) & 1023;        // 64-aligned
        bf16* O = (bf16*)OutP;
        #pragma unroll
        for (int i = 0; i < 4; i++) {
            int row0 = m0 + wm + i * 16 + q * 4;
            #pragma unroll
            for (int r = 0; r < 4; r++) {
                int f = row0 + r;                  // feature index
                int h = f >> 6, d = f & 63;
                float bv = bias[f];
                size_t idx = ((((size_t)bbt * 16 + h) * 64 + d) << 10) + tbase + lr * 4;
                *(uint2*)(&O[idx]) = pack4(acc[i][0][r] + bv, acc[i][1][r] + bv,
                                           acc[i][2][r] + bv, acc[i][3][r] + bv);
            }
        }
    } else {
        #pragma unroll
        for (int i = 0; i < 4; i++) {
            int row0 = m0 + wm + i * 16 + q * 4;
            #pragma unroll
            for (int j = 0; j < 4; j++) {
                int col = n0 + wn + j * 16 + lr;
                float bv = bias[col];
                #pragma unroll
                for (int r = 0; r < 4; r++) {
                    float val = acc[i][j][r] + bv;
                    int mrow = row0 + r;
                    if (mode == 3) {
                        ((float*)OutP)[(size_t)mrow * 1024 + col] = val;
                    } else {
                        int bb = mrow >> 10, t = mrow & 1023;
                        int h  = col >> 6,   d = col & 63;
                        size_t idx;
                        if (mode == 2)
                            idx = ((((size_t)bb * 16 + h) * 64 + d) << 10) + tperm(t);
                        else
                            idx = ((((size_t)bb * 16 + h) << 10) + t) * 64 + d;
                        ((bf16*)OutP)[idx] = __float2bfloat16(val);
                    }
                }
            }
        }
    }
}

// ---------------------------------------------------------------------------
// Output GEMM: 64(M) x 128(N) tiles, BK=64, 3-DEEP LDS RING + counted vmcnt.
// Kept byte-identical to r2 (never indicted by per-dispatch data; single-
// variable discipline -- if the static-buffer theory proves out on
// gemm_batch this round, port it here next round).
// ---------------------------------------------------------------------------
template<bool WBF>
__global__ __launch_bounds__(256) void gemm_out(const bf16* __restrict__ A,
                                                const void* __restrict__ Wp,
                                                const float* __restrict__ bias,
                                                float* __restrict__ Out)
{
    constexpr int K = 1024;
    __shared__ bf16 As[3][64 * 64];     // 24 KB
    __shared__ bf16 Bs[3][128 * 64];    // 48 KB

    const int tid = threadIdx.x;
    const int lid = blockIdx.x + 8 * blockIdx.y;       // 0..511
    const int mt  = (lid & 7) * 8 + (lid >> 6);        // 0..63 (XCD-grouped)
    const int nt  = (lid >> 3) & 7;                    // 0..7
    const int n0  = nt * 128;
    const int m0  = mt * 64;
    const int lane = tid & 63;
    const int wave = tid >> 6;
    const int wm   = (wave >> 1) * 32;
    const int wn   = (wave & 1) * 64;
    const int lr   = lane & 15;
    const int q    = lane >> 4;

    const int sr = tid >> 1;
    const int sc = (tid & 1) * 32;

    // B tile 128x64 = 1024 chunks of 16B (8 chunks/row), 4 per thread
    int rb[4], cb4[4];
    #pragma unroll
    for (int gg = 0; gg < 4; gg++) {
        int D = wave * 256 + gg * 64 + lane;
        rb[gg]  = D >> 3;
        cb4[gg] = (D & 7) * 8;
    }
    // A tile 64x64 = 512 chunks, 2 per thread
    int ra[2], ca4[2];
    #pragma unroll
    for (int gg = 0; gg < 2; gg++) {
        int D = wave * 128 + gg * 64 + lane;
        ra[gg]  = D >> 3;
        ca4[gg] = (D & 7) * 8;
    }

    auto stage = [&](int k0, int pb) {
        if (WBF) {
            const bf16* W = (const bf16*)Wp;
            #pragma unroll
            for (int gg = 0; gg < 4; gg++)
                gl2lds16(&W[(size_t)(n0 + rb[gg]) * K + k0 + cb4[gg]],
                         &Bs[pb][(wave * 256 + gg * 64) * 8]);
        } else {
            const float* W = (const float*)Wp;
            const float* src = &W[(size_t)(n0 + sr) * K + k0 + sc];
            #pragma unroll
            for (int c = 0; c < 4; c++) {
                float4 f0 = ((const float4*)src)[2 * c];
                float4 f1 = ((const float4*)src)[2 * c + 1];
                *(uint4*)(&Bs[pb][sr * 64 + sc + c * 8]) = pack8(f0, f1);
            }
        }
        #pragma unroll
        for (int gg = 0; gg < 2; gg++)
            gl2lds16(&A[(size_t)(m0 + ra[gg]) * K + k0 + ca4[gg]],
                     &As[pb][(wave * 128 + gg * 64) * 8]);
    };

    f4 acc[2][4];
    #pragma unroll
    for (int i = 0; i < 2; i++)
        #pragma unroll
        for (int j = 0; j < 4; j++) acc[i][j] = f4{0.f, 0.f, 0.f, 0.f};

    stage(0, 0);
    stage(64, 1);
    if (WBF) {
        asm volatile("s_waitcnt vmcnt(6)" ::: "memory");
        __builtin_amdgcn_s_barrier();
    } else {
        __syncthreads();
    }

    int cb = 0;
    for (int kt = 0; kt < 16; kt++) {
        if (kt < 14) {
            int sb = cb + 2; if (sb >= 3) sb -= 3;
            stage((kt + 2) * 64, sb);
        }

        #pragma unroll
        for (int kk = 0; kk < 2; kk++) {
            frag af[2], bfr[4];
            #pragma unroll
            for (int i = 0; i < 2; i++)
                af[i] = *(const frag*)(&As[cb][(wm + i * 16 + lr) * 64 + kk * 32 + q * 8]);
            #pragma unroll
            for (int j = 0; j < 4; j++)
                bfr[j] = *(const frag*)(&Bs[cb][(wn + j * 16 + lr) * 64 + kk * 32 + q * 8]);
            #pragma unroll
            for (int i = 0; i < 2; i++)
                #pragma unroll
                for (int j = 0; j < 4; j++)
                    acc[i][j] = __builtin_amdgcn_mfma_f32_16x16x32_bf16(af[i], bfr[j], acc[i][j], 0, 0, 0);
        }

        if (kt < 15) {
            if (WBF) {
                if (kt < 14) asm volatile("s_waitcnt vmcnt(6)" ::: "memory");
                else         asm volatile("s_waitcnt vmcnt(0)" ::: "memory");
                __builtin_amdgcn_s_barrier();
            } else {
                __syncthreads();
            }
        }
        cb = cb + 1; if (cb == 3) cb = 0;
    }

    #pragma unroll
    for (int i = 0; i < 2; i++) {
        int row0 = m0 + wm + i * 16 + q * 4;
        #pragma unroll
        for (int j = 0; j < 4; j++) {
            int col = n0 + wn + j * 16 + lr;
            float bv = bias[col];
            #pragma unroll
            for (int r = 0; r < 4; r++)
                Out[(size_t)(row0 + r) * 1024 + col] = acc[i][j][r] + bv;
        }
    }
}

// ---------------------------------------------------------------------------
// Flash attention: REVERTED to the r2 (measured-good) 32 q-rows/wave
// structure: 128 rows/block, grid (64 bh, 8 qtiles).  r3's 16-row variant
// regressed ~8us total: halving rows/wave halves MFMA per K/V staging +
// per-tile serial chain while doubling K/V traffic; LDS per block stayed
// high enough that waves/CU didn't rise (4 blocks by grid, 3 by LDS).
// __launch_bounds__(256,3) pins 3 waves/SIMD (r6/r7 config).
// Fixed-shift softmax (exact), mask folded into exp bias.  P strip padded
// to 72.  P stored key-permuted (pos=lr*4+j); vhT carries the same perm.
// Double-buffered K/V via glds, 1 barrier/tile.  LDS 50KB.
// ---------------------------------------------------------------------------
__global__ __launch_bounds__(256, 3) void attn_kernel(const bf16* __restrict__ qh,
                                                      const bf16* __restrict__ kh,
                                                      const bf16* __restrict__ vhT,
                                                      const float* __restrict__ wts,
                                                      bf16* __restrict__ att)
{
    constexpr int LDP = 72;
    __shared__ bf16 Ks[2][64 * 64];
    __shared__ bf16 Vs[2][64 * 64];
    __shared__ bf16 Plds[4][32 * LDP];

    const int tid  = threadIdx.x;
    const int lane = tid & 63;
    const int wave = tid >> 6;
    const int lr   = lane & 15;
    const int q    = lane >> 4;
    const int bh   = blockIdx.x;               // 0..63
    const int bb   = bh >> 4;
    const int h    = bh & 15;
    const int q0w  = blockIdx.y * 128 + wave * 32;
    const size_t base = (size_t)bh * 1024 * 64;

    const int cA = wave * 128 + lane;
    const int cB = cA + 64;
    const int rowA = cA >> 3, gA = ((cA & 7) ^ (rowA & 7)) * 8;
    const int rowB = cB >> 3, gB = ((cB & 7) ^ (rowB & 7)) * 8;

    frag aq[2][2];
    #pragma unroll
    for (int rf = 0; rf < 2; rf++)
        #pragma unroll
        for (int ks = 0; ks < 2; ks++)
            aq[rf][ks] = *(const frag*)(&qh[base + (size_t)(q0w + rf * 16 + lr) * 64 + ks * 32 + q * 8]);

    float rs[2][4];
    f4 o[2][4];
    #pragma unroll
    for (int rf = 0; rf < 2; rf++)
        #pragma unroll
        for (int j = 0; j < 4; j++) {
            o[rf][j] = f4{0.f, 0.f, 0.f, 0.f};
            rs[rf][j] = 0.f;
        }

    gl2lds16(&kh [base + (size_t)rowA * 64 + gA],   &Ks[0][wave * 1024]);
    gl2lds16(&kh [base + (size_t)rowB * 64 + gB],   &Ks[0][wave * 1024 + 512]);
    gl2lds16(&vhT[base + (size_t)rowA * 1024 + gA], &Vs[0][wave * 1024]);
    gl2lds16(&vhT[base + (size_t)rowB * 1024 + gB], &Vs[0][wave * 1024 + 512]);
    __syncthreads();

    for (int t = 0; t < 16; t++) {
        const int k0  = t * 64;
        const int buf = t & 1;
        if (t < 15) {
            int kn = k0 + 64;
            gl2lds16(&kh [base + (size_t)(kn + rowA) * 64 + gA],  &Ks[buf ^ 1][wave * 1024]);
            gl2lds16(&kh [base + (size_t)(kn + rowB) * 64 + gB],  &Ks[buf ^ 1][wave * 1024 + 512]);
            gl2lds16(&vhT[base + (size_t)rowA * 1024 + kn + gA], &Vs[buf ^ 1][wave * 1024]);
            gl2lds16(&vhT[base + (size_t)rowB * 1024 + kn + gB], &Vs[buf ^ 1][wave * 1024 + 512]);
        }

        // per-key scale; mask folded into bias (exp2(-1e30)=0)
        float sc2[4], eb[4];
        #pragma unroll
        for (int j = 0; j < 4; j++) {
            float w = wts[bb * 1024 + k0 + j * 16 + lr];
            sc2[j] = SC2K * w * w;
            eb[j]  = (w < WEPS) ? -1e30f : EBIAS;
        }

        // K fragments (shared across both row-groups)
        frag kb[4][2];
        #pragma unroll
        for (int j = 0; j < 4; j++) {
            int rowj = j * 16 + lr;
            kb[j][0] = *(const frag*)(&Ks[buf][rowj * 64 + (((q    ) ^ (rowj & 7)) * 8)]);
            kb[j][1] = *(const frag*)(&Ks[buf][rowj * 64 + (((q + 4) ^ (rowj & 7)) * 8)]);
        }

        // S = Q K^T for both 16-row groups
        #pragma unroll
        for (int rf = 0; rf < 2; rf++) {
            f4 s[4];
            #pragma unroll
            for (int j = 0; j < 4; j++) {
                f4 z = f4{0.f, 0.f, 0.f, 0.f};
                s[j] = __builtin_amdgcn_mfma_f32_16x16x32_bf16(aq[rf][0], kb[j][0], z, 0, 0, 0);
                s[j] = __builtin_amdgcn_mfma_f32_16x16x32_bf16(aq[rf][1], kb[j][1], s[j], 0, 0, 0);
            }
            float p[4][4];
            #pragma unroll
            for (int j = 0; j < 4; j++)
                #pragma unroll
                for (int r = 0; r < 4; r++) {
                    p[j][r] = __builtin_amdgcn_exp2f(fmaf(s[j][r], sc2[j], eb[j]));
                    rs[rf][r] += p[j][r];
                }
            #pragma unroll
            for (int r = 0; r < 4; r++)
                *(uint2*)(&Plds[wave][(rf * 16 + q * 4 + r) * LDP + lr * 4]) =
                    pack4(p[0][r], p[1][r], p[2][r], p[3][r]);
        }

        // V fragments (shared across both row-groups)
        frag vb[4][2];
        #pragma unroll
        for (int j = 0; j < 4; j++) {
            int rowj = j * 16 + lr;
            vb[j][0] = *(const frag*)(&Vs[buf][rowj * 64 + (((q    ) ^ (rowj & 7)) * 8)]);
            vb[j][1] = *(const frag*)(&Vs[buf][rowj * 64 + (((q + 4) ^ (rowj & 7)) * 8)]);
        }

        #pragma unroll
        for (int rf = 0; rf < 2; rf++) {
            frag ap0 = *(const frag*)(&Plds[wave][(rf * 16 + lr) * LDP + q * 8]);
            frag ap1 = *(const frag*)(&Plds[wave][(rf * 16 + lr) * LDP + 32 + q * 8]);
            #pragma unroll
            for (int j = 0; j < 4; j++) {
                o[rf][j] = __builtin_amdgcn_mfma_f32_16x16x32_bf16(ap0, vb[j][0], o[rf][j], 0, 0, 0);
                o[rf][j] = __builtin_amdgcn_mfma_f32_16x16x32_bf16(ap1, vb[j][1], o[rf][j], 0, 0, 0);
            }
        }
        __syncthreads();
    }

    #pragma unroll
    for (int off = 1; off < 16; off <<= 1)
        #pragma unroll
        for (int rf = 0; rf < 2; rf++)
            #pragma unroll
            for (int r = 0; r < 4; r++)
                rs[rf][r] += __shfl_xor(rs[rf][r], off, 64);

    #pragma unroll
    for (int rf = 0; rf < 2; rf++) {
        float inv[4];
        #pragma unroll
        for (int r = 0; r < 4; r++) inv[r] = 1.0f / rs[rf][r];
        const int t0 = q0w + rf * 16 + q * 4;
        #pragma unroll
        for (int j = 0; j < 4; j++) {
            int d = h * 64 + j * 16 + lr;
            #pragma unroll
            for (int r = 0; r < 4; r++)
                att[((size_t)bb * 1024 + t0 + r) * 1024 + d] =
                    __float2bfloat16(o[rf][j][r] * inv[r]);
        }
    }
}

// ---------------------------------------------------------------------------
extern "C" void kernel_launch(void* const* d_in, const int* in_sizes, int n_in,
                              void* d_out, int out_size, void* d_ws, size_t ws_size,
                              hipStream_t stream)
{
    const float* q   = (const float*)d_in[0];
    const float* k   = (const float*)d_in[1];
    const float* v   = (const float*)d_in[2];
    const float* wts = (const float*)d_in[3];
    const float* Wq  = (const float*)d_in[4];
    const float* bq  = (const float*)d_in[5];
    const float* Wk  = (const float*)d_in[6];
    const float* bk  = (const float*)d_in[7];
    const float* Wv  = (const float*)d_in[8];
    const float* bv  = (const float*)d_in[9];
    const float* Wo  = (const float*)d_in[10];
    const float* bo  = (const float*)d_in[11];
    float* out = (float*)d_out;

    const long long Mi = 1024 * 1024;
    bf16* qh  = (bf16*)d_ws;
    bf16* kh  = qh  + 4 * Mi;
    bf16* vhT = kh  + 4 * Mi;
    bf16* att = vhT + 4 * Mi;
    bf16* cvt = att + 4 * Mi;
    const size_t base_bytes = (size_t)32 * Mi;

    dim3 blk(256);

    if (ws_size >= base_bytes + (size_t)32 * Mi) {
        // FULL: pre-convert q,k,v + all weights to bf16
        CvtArgs ca{};
        ca.src[0] = q;  ca.src[1] = k;  ca.src[2] = v;
        ca.src[3] = Wq; ca.src[4] = Wk; ca.src[5] = Wv; ca.src[6] = Wo;
        long long bnd[8] = {0, 4*Mi, 8*Mi, 12*Mi, 13*Mi, 14*Mi, 15*Mi, 16*Mi};
        for (int i = 0; i < 8; i++) ca.bounds[i] = bnd[i];
        ca.total = 16 * Mi;
        cvt_kernel<<<8192, blk, 0, stream>>>(ca, cvt);

        GemmBatch gq{};
        gq.A[0] = cvt;          gq.A[1] = cvt + 4*Mi;   gq.A[2] = cvt + 14*Mi; // z2: A=Wv (swapped)
        gq.W[0] = cvt + 12*Mi;  gq.W[1] = cvt + 13*Mi;  gq.W[2] = cvt + 8*Mi;  // z2: W=v
        gq.bias[0] = bq; gq.bias[1] = bk; gq.bias[2] = bv;
        gq.Out[0] = qh;  gq.Out[1] = kh;  gq.Out[2] = vhT;
        gq.mode[0] = 0;  gq.mode[1] = 0;  gq.mode[2] = 4;
        gemm_batch<true, true><<<dim3(8, 32, 3), blk, 0, stream>>>(gq);

        attn_kernel<<<dim3(64, 8), blk, 0, stream>>>(qh, kh, vhT, wts, att);

        gemm_out<true><<<dim3(8, 64), blk, 0, stream>>>(att, cvt + 15*Mi, bo, out);
    } else if (ws_size >= base_bytes + (size_t)8 * Mi) {
        // HYBRID: pre-convert weights only
        CvtArgs ca{};
        ca.src[0] = Wq; ca.src[1] = Wk; ca.src[2] = Wv; ca.src[3] = Wo;
        long long bnd[8] = {0, 1*Mi, 2*Mi, 3*Mi, 4*Mi, 4*Mi, 4*Mi, 4*Mi};
        for (int i = 0; i < 8; i++) ca.bounds[i] = bnd[i];
        ca.total = 4 * Mi;
        cvt_kernel<<<2048, blk, 0, stream>>>(ca, cvt);

        GemmBatch gq{};
        gq.A[0] = q; gq.A[1] = k; gq.A[2] = v;
        gq.W[0] = cvt; gq.W[1] = cvt + 1*Mi; gq.W[2] = cvt + 2*Mi;
        gq.bias[0] = bq; gq.bias[1] = bk; gq.bias[2] = bv;
        gq.Out[0] = qh;  gq.Out[1] = kh;  gq.Out[2] = vhT;
        gq.mode[0] = 0;  gq.mode[1] = 0;  gq.mode[2] = 2;
        gemm_batch<false, true><<<dim3(8, 32, 3), blk, 0, stream>>>(gq);

        attn_kernel<<<dim3(64, 8), blk, 0, stream>>>(qh, kh, vhT, wts, att);

        gemm_out<true><<<dim3(8, 64), blk, 0, stream>>>(att, cvt + 3*Mi, bo, out);
    } else {
        // FALLBACK: no conversions
        GemmBatch gq{};
        gq.A[0] = q; gq.A[1] = k; gq.A[2] = v;
        gq.W[0] = Wq; gq.W[1] = Wk; gq.W[2] = Wv;
        gq.bias[0] = bq; gq.bias[1] = bk; gq.bias[2] = bv;
        gq.Out[0] = qh;  gq.Out[1] = kh;  gq.Out[2] = vhT;
        gq.mode[0] = 0;  gq.mode[1] = 0;  gq.mode[2] = 2;
        gemm_batch<false, false><<<dim3(8, 32, 3), blk, 0, stream>>>(gq);

        attn_kernel<<<dim3(64, 8), blk, 0, stream>>>(qh, kh, vhT, wts, att);

        gemm_out<false><<<dim3(8, 64), blk, 0, stream>>>(att, Wo, bo, out);
    }
}

// Round 5
// 205.740 us; speedup vs baseline: 1.0567x; 1.0051x over previous
//
#include <hip/hip_runtime.h>
#include <hip/hip_bf16.h>
#include <stdint.h>

using frag = __attribute__((ext_vector_type(8))) short;   // 8 bf16 in 4 VGPRs
using f4   = __attribute__((ext_vector_type(4))) float;   // 4 fp32 acc
using bf16 = __hip_bfloat16;

// B=4, T=1024, E=1024, H=16, Dk=64.  Global I/O fp32; compute bf16 MFMA.
static constexpr float WEPS = 1e-5f;
// p = exp(s*sc - 8) = exp2(s*(sc*log2e) - 8*log2e); sc = 0.125*w*w
static constexpr float SC2K  = 0.125f * 1.44269504f;   // 0.18033688
static constexpr float EBIAS = -8.0f * 1.44269504f;    // -11.5415603

#define AS1(p) ((const __attribute__((address_space(1))) void*)(p))
#define AS3(p) ((__attribute__((address_space(3))) void*)(p))

__device__ __forceinline__ void gl2lds16(const void* g, void* l) {
    __builtin_amdgcn_global_load_lds(AS1(g), AS3(l), 16, 0, 0);
}

__device__ inline uint4 pack8(float4 a, float4 b) {
    union { bf16 h[8]; uint4 u; } x;
    x.h[0] = __float2bfloat16(a.x); x.h[1] = __float2bfloat16(a.y);
    x.h[2] = __float2bfloat16(a.z); x.h[3] = __float2bfloat16(a.w);
    x.h[4] = __float2bfloat16(b.x); x.h[5] = __float2bfloat16(b.y);
    x.h[6] = __float2bfloat16(b.z); x.h[7] = __float2bfloat16(b.w);
    return x.u;
}

__device__ __forceinline__ uint2 pack4(float a, float b, float c, float d) {
    union { bf16 h[4]; uint2 u; } x;
    x.h[0] = __float2bfloat16(a); x.h[1] = __float2bfloat16(b);
    x.h[2] = __float2bfloat16(c); x.h[3] = __float2bfloat16(d);
    return x.u;
}

// key-position permutation within each 64-token group:
// pos(j*16+lr) = lr*4+j.  Applied to vhT columns AND P columns identically.
__device__ __forceinline__ int tperm(int t) {
    return (t & ~63) | (((t & 15) << 2) | ((t >> 4) & 3));
}

// ---------------------------------------------------------------------------
// Multi-segment fp32 -> bf16 convert into one contiguous bf16 region.
// ---------------------------------------------------------------------------
struct CvtArgs {
    const float* src[7];
    long long    bounds[8];
    long long    total;
};

__global__ __launch_bounds__(256) void cvt_kernel(CvtArgs a, bf16* __restrict__ dst)
{
    long long e = ((long long)blockIdx.x * 256 + threadIdx.x) * 8;
    if (e >= a.total) return;
    int s = 0;
    while (e >= a.bounds[s + 1]) s++;
    const float* src = a.src[s] + (e - a.bounds[s]);
    float4 f0 = ((const float4*)src)[0];
    float4 f1 = ((const float4*)src)[1];
    *(uint4*)(dst + e) = pack8(f0, f1);
}

// ---------------------------------------------------------------------------
// Batched GEMM, 128x128 tile, BK=32, DOUBLE-BUFFERED LDS (1 barrier/iter).
// PARKED at the r2 measured-best structure (49.6us, MfmaUtil 19.5%).
// Pipeline history: r9 runtime-ring counted-vmcnt = 70us (runtime index
// defeats LDS-DMA/ds_read alias disambiguation -> compiler pre-drains);
// r12 static-3buf counted-vmcnt = 50.8us (pipeline gain offset by LDS
// 48KB occupancy cost).  Structure-bound at ~516 TF; 256^2 8-phase is
// geometry-blocked (M=4096,N=1024 -> 192 blocks = 75% CU fill).
// XCD swizzle: big=(lid&7)*4+(lid>>6) (r8: FETCH 101->37MB).
// Out[m,n] = sum_k A[m,k]*W[n,k] + bias[n]
// mode 0: (B,H,T,Dk) bf16 | mode 2: (B,H,Dk,T) scatter (key-permuted)
// mode 3: fp32 row-major  | mode 4: swapped operands -> (B,H,Dk,T) key-permuted
// ---------------------------------------------------------------------------
struct GemmBatch {
    const void*  A[3];
    const void*  W[3];
    const float* bias[3];
    void*        Out[3];
    int          mode[3];
};

template<bool ABF, bool WBF>
__global__ __launch_bounds__(256) void gemm_batch(GemmBatch g)
{
    constexpr int K = 1024;
    __shared__ bf16 As[2][128 * 32];
    __shared__ bf16 Bs[2][128 * 32];

    const int z = blockIdx.z;
    const void*  Ap   = g.A[z];
    const void*  Wp   = g.W[z];
    const float* bias = g.bias[z];
    void*        OutP = g.Out[z];
    const int    mode = g.mode[z];

    const int tid = threadIdx.x;
    const int lid = blockIdx.x + 8 * blockIdx.y;       // 0..255
    const int big   = (lid & 7) * 4 + (lid >> 6);      // 0..31 (XCD-grouped)
    const int small = (lid >> 3) & 7;                  // 0..7
    int m0, n0;
    if (mode == 4) { m0 = small * 128; n0 = big * 128; }
    else           { m0 = big * 128;   n0 = small * 128; }

    const int lane = tid & 63;
    const int wave = tid >> 6;
    const int wm   = (wave >> 1) * 64;
    const int wn   = (wave & 1) * 64;
    const int lr   = lane & 15;
    const int q    = lane >> 4;

    const int sr = tid >> 1;
    const int sc = (tid & 1) * 16;

    const int c0 = wave * 128 + lane;
    const int c1 = c0 + 64;
    const int r0 = c0 >> 2, col0 = (c0 & 3) * 8;
    const int r1 = c1 >> 2, col1 = (c1 & 3) * 8;

    auto stage = [&](int k0, int pb) {
        if (WBF) {
            const bf16* W = (const bf16*)Wp;
            gl2lds16(&W[(size_t)(n0 + r0) * K + k0 + col0], &Bs[pb][wave * 1024]);
            gl2lds16(&W[(size_t)(n0 + r1) * K + k0 + col1], &Bs[pb][wave * 1024 + 512]);
        } else {
            const float* W = (const float*)Wp;
            const float* src = &W[(size_t)(n0 + sr) * K + k0 + sc];
            float4 f0 = ((const float4*)src)[0];
            float4 f1 = ((const float4*)src)[1];
            float4 f2 = ((const float4*)src)[2];
            float4 f3 = ((const float4*)src)[3];
            *(uint4*)(&Bs[pb][sr * 32 + sc])     = pack8(f0, f1);
            *(uint4*)(&Bs[pb][sr * 32 + sc + 8]) = pack8(f2, f3);
        }
        if (ABF) {
            const bf16* A = (const bf16*)Ap;
            gl2lds16(&A[(size_t)(m0 + r0) * K + k0 + col0], &As[pb][wave * 1024]);
            gl2lds16(&A[(size_t)(m0 + r1) * K + k0 + col1], &As[pb][wave * 1024 + 512]);
        } else {
            const float* A = (const float*)Ap;
            const float* src = &A[(size_t)(m0 + sr) * K + k0 + sc];
            float4 f0 = ((const float4*)src)[0];
            float4 f1 = ((const float4*)src)[1];
            float4 f2 = ((const float4*)src)[2];
            float4 f3 = ((const float4*)src)[3];
            *(uint4*)(&As[pb][sr * 32 + sc])     = pack8(f0, f1);
            *(uint4*)(&As[pb][sr * 32 + sc + 8]) = pack8(f2, f3);
        }
    };

    f4 acc[4][4];
    #pragma unroll
    for (int i = 0; i < 4; i++)
        #pragma unroll
        for (int j = 0; j < 4; j++) acc[i][j] = f4{0.f, 0.f, 0.f, 0.f};

    stage(0, 0);
    __syncthreads();

    for (int kt = 0; kt < 32; kt++) {
        const int cb = kt & 1;
        if (kt < 31) stage((kt + 1) * 32, cb ^ 1);

        frag af[4], bfr[4];
        #pragma unroll
        for (int i = 0; i < 4; i++)
            af[i] = *(const frag*)(&As[cb][(wm + i * 16 + lr) * 32 + q * 8]);
        #pragma unroll
        for (int j = 0; j < 4; j++)
            bfr[j] = *(const frag*)(&Bs[cb][(wn + j * 16 + lr) * 32 + q * 8]);
        #pragma unroll
        for (int i = 0; i < 4; i++)
            #pragma unroll
            for (int j = 0; j < 4; j++)
                acc[i][j] = __builtin_amdgcn_mfma_f32_16x16x32_bf16(af[i], bfr[j], acc[i][j], 0, 0, 0);
        __syncthreads();
    }

    // epilogue: D row = quad*4+reg, col = lane&15
    if (mode == 4) {
        const int bbt   = (n0 + wn) >> 10;
        const int tbase = (n0 + wn) & 1023;        // 64-aligned
        bf16* O = (bf16*)OutP;
        #pragma unroll
        for (int i = 0; i < 4; i++) {
            int row0 = m0 + wm + i * 16 + q * 4;
            #pragma unroll
            for (int r = 0; r < 4; r++) {
                int f = row0 + r;                  // feature index
                int h = f >> 6, d = f & 63;
                float bv = bias[f];
                size_t idx = ((((size_t)bbt * 16 + h) * 64 + d) << 10) + tbase + lr * 4;
                *(uint2*)(&O[idx]) = pack4(acc[i][0][r] + bv, acc[i][1][r] + bv,
                                           acc[i][2][r] + bv, acc[i][3][r] + bv);
            }
        }
    } else {
        #pragma unroll
        for (int i = 0; i < 4; i++) {
            int row0 = m0 + wm + i * 16 + q * 4;
            #pragma unroll
            for (int j = 0; j < 4; j++) {
                int col = n0 + wn + j * 16 + lr;
                float bv = bias[col];
                #pragma unroll
                for (int r = 0; r < 4; r++) {
                    float val = acc[i][j][r] + bv;
                    int mrow = row0 + r;
                    if (mode == 3) {
                        ((float*)OutP)[(size_t)mrow * 1024 + col] = val;
                    } else {
                        int bb = mrow >> 10, t = mrow & 1023;
                        int h  = col >> 6,   d = col & 63;
                        size_t idx;
                        if (mode == 2)
                            idx = ((((size_t)bb * 16 + h) * 64 + d) << 10) + tperm(t);
                        else
                            idx = ((((size_t)bb * 16 + h) << 10) + t) * 64 + d;
                        ((bf16*)OutP)[idx] = __float2bfloat16(val);
                    }
                }
            }
        }
    }
}

// ---------------------------------------------------------------------------
// Output GEMM: 64(M) x 128(N) tiles, BK=64, depth-2 counted-vmcnt pipeline.
// r13: converted the runtime-indexed ring (As[pb], pb runtime -- the exact
// pattern that cost gemm_batch +40% in r9 via alias-forced pre-drains) to
// STATICALLY-INDEXED 3 buffers + 3x-unrolled schedule (r12 pattern).  At
// 2 blocks/CU this kernel has the least TLP in the pipeline, so removing
// compiler pre-drains should pay most here.  6 gl2lds/thread/tile ->
// steady-state vmcnt(6): retire tile t+1, keep t+2's 6 loads in flight
// across each barrier.  Ledger: prologue t0,t1; 4x3 unrolled body; 2-tile
// tail.  Write-safety: each stage(b) follows the barrier after b's last
// compute.  LDS 72KB -> 2 blocks/CU (same as before).  XCD swizzle.
// ---------------------------------------------------------------------------
template<bool WBF>
__global__ __launch_bounds__(256) void gemm_out(const bf16* __restrict__ A,
                                                const void* __restrict__ Wp,
                                                const float* __restrict__ bias,
                                                float* __restrict__ Out)
{
    constexpr int K = 1024;
    __shared__ bf16 As0[64 * 64], As1[64 * 64], As2[64 * 64];      // 3x8 KB
    __shared__ bf16 Bs0[128 * 64], Bs1[128 * 64], Bs2[128 * 64];   // 3x16 KB

    const int tid = threadIdx.x;
    const int lid = blockIdx.x + 8 * blockIdx.y;       // 0..511
    const int mt  = (lid & 7) * 8 + (lid >> 6);        // 0..63 (XCD-grouped)
    const int nt  = (lid >> 3) & 7;                    // 0..7
    const int n0  = nt * 128;
    const int m0  = mt * 64;
    const int lane = tid & 63;
    const int wave = tid >> 6;
    const int wm   = (wave >> 1) * 32;
    const int wn   = (wave & 1) * 64;
    const int lr   = lane & 15;
    const int q    = lane >> 4;

    const int sr = tid >> 1;
    const int sc = (tid & 1) * 32;

    // B tile 128x64 = 1024 chunks of 16B (8 chunks/row), 4 per thread
    int rb[4], cb4[4];
    #pragma unroll
    for (int gg = 0; gg < 4; gg++) {
        int D = wave * 256 + gg * 64 + lane;
        rb[gg]  = D >> 3;
        cb4[gg] = (D & 7) * 8;
    }
    // A tile 64x64 = 512 chunks, 2 per thread
    int ra[2], ca4[2];
    #pragma unroll
    for (int gg = 0; gg < 2; gg++) {
        int D = wave * 128 + gg * 64 + lane;
        ra[gg]  = D >> 3;
        ca4[gg] = (D & 7) * 8;
    }

    auto stage = [&](int k0, bf16* Asd, bf16* Bsd) {
        if (WBF) {
            const bf16* W = (const bf16*)Wp;
            #pragma unroll
            for (int gg = 0; gg < 4; gg++)
                gl2lds16(&W[(size_t)(n0 + rb[gg]) * K + k0 + cb4[gg]],
                         &Bsd[(wave * 256 + gg * 64) * 8]);
        } else {
            const float* W = (const float*)Wp;
            const float* src = &W[(size_t)(n0 + sr) * K + k0 + sc];
            #pragma unroll
            for (int c = 0; c < 4; c++) {
                float4 f0 = ((const float4*)src)[2 * c];
                float4 f1 = ((const float4*)src)[2 * c + 1];
                *(uint4*)(&Bsd[sr * 64 + sc + c * 8]) = pack8(f0, f1);
            }
        }
        #pragma unroll
        for (int gg = 0; gg < 2; gg++)
            gl2lds16(&A[(size_t)(m0 + ra[gg]) * K + k0 + ca4[gg]],
                     &Asd[(wave * 128 + gg * 64) * 8]);
    };

    f4 acc[2][4];
    #pragma unroll
    for (int i = 0; i < 2; i++)
        #pragma unroll
        for (int j = 0; j < 4; j++) acc[i][j] = f4{0.f, 0.f, 0.f, 0.f};

    auto compute = [&](const bf16* Asp, const bf16* Bsp) {
        #pragma unroll
        for (int kk = 0; kk < 2; kk++) {
            frag af[2], bfr[4];
            #pragma unroll
            for (int i = 0; i < 2; i++)
                af[i] = *(const frag*)(&Asp[(wm + i * 16 + lr) * 64 + kk * 32 + q * 8]);
            #pragma unroll
            for (int j = 0; j < 4; j++)
                bfr[j] = *(const frag*)(&Bsp[(wn + j * 16 + lr) * 64 + kk * 32 + q * 8]);
            #pragma unroll
            for (int i = 0; i < 2; i++)
                #pragma unroll
                for (int j = 0; j < 4; j++)
                    acc[i][j] = __builtin_amdgcn_mfma_f32_16x16x32_bf16(af[i], bfr[j], acc[i][j], 0, 0, 0);
        }
    };

    if (WBF) {
        stage(0,   As0, Bs0);                          // t0
        stage(64,  As1, Bs1);                          // t1
        asm volatile("s_waitcnt vmcnt(6)" ::: "memory");   // t0 done, t1 flying
        __builtin_amdgcn_s_barrier();

        for (int m = 0; m < 4; m++) {
            const int kb = m * 192;                    // tile 3m at k0 = kb
            stage(kb + 128, As2, Bs2);                 // t_{3m+2}
            compute(As0, Bs0);                         // t_{3m}
            asm volatile("s_waitcnt vmcnt(6)" ::: "memory");
            __builtin_amdgcn_s_barrier();

            stage(kb + 192, As0, Bs0);                 // t_{3m+3}
            compute(As1, Bs1);                         // t_{3m+1}
            asm volatile("s_waitcnt vmcnt(6)" ::: "memory");
            __builtin_amdgcn_s_barrier();

            stage(kb + 256, As1, Bs1);                 // t_{3m+4}
            compute(As2, Bs2);                         // t_{3m+2}
            asm volatile("s_waitcnt vmcnt(6)" ::: "memory");
            __builtin_amdgcn_s_barrier();
        }
        // staged t0..t13; computed t0..t11
        stage(896, As2, Bs2);                          // t14
        compute(As0, Bs0);                             // t12
        asm volatile("s_waitcnt vmcnt(6)" ::: "memory");
        __builtin_amdgcn_s_barrier();
        stage(960, As0, Bs0);                          // t15
        compute(As1, Bs1);                             // t13
        asm volatile("s_waitcnt vmcnt(6)" ::: "memory");
        __builtin_amdgcn_s_barrier();
        compute(As2, Bs2);                             // t14
        asm volatile("s_waitcnt vmcnt(0)" ::: "memory");
        __builtin_amdgcn_s_barrier();
        compute(As0, Bs0);                             // t15
    } else {
        stage(0,   As0, Bs0);
        stage(64,  As1, Bs1);
        __syncthreads();
        for (int m = 0; m < 4; m++) {
            const int kb = m * 192;
            stage(kb + 128, As2, Bs2);
            compute(As0, Bs0);
            __syncthreads();
            stage(kb + 192, As0, Bs0);
            compute(As1, Bs1);
            __syncthreads();
            stage(kb + 256, As1, Bs1);
            compute(As2, Bs2);
            __syncthreads();
        }
        stage(896, As2, Bs2);
        compute(As0, Bs0);
        __syncthreads();
        stage(960, As0, Bs0);
        compute(As1, Bs1);
        __syncthreads();
        compute(As2, Bs2);
        __syncthreads();
        compute(As0, Bs0);
    }

    #pragma unroll
    for (int i = 0; i < 2; i++) {
        int row0 = m0 + wm + i * 16 + q * 4;
        #pragma unroll
        for (int j = 0; j < 4; j++) {
            int col = n0 + wn + j * 16 + lr;
            float bv = bias[col];
            #pragma unroll
            for (int r = 0; r < 4; r++)
                Out[(size_t)(row0 + r) * 1024 + col] = acc[i][j][r] + bv;
        }
    }
}

// ---------------------------------------------------------------------------
// Flash attention: r2 measured-good structure (32 q-rows/wave, 128/block,
// grid (64 bh, 8 qtiles)) + r13 addition: T5 s_setprio(1) around the QK
// and PV MFMA clusters.  Mechanism (m191, +4-7% on attn): 2 independent
// blocks/CU with no inter-block sync are at different phases; setprio
// makes the CU favor the MFMA-issuing wave over the load/VALU-issuing
// ones.  Pure scheduler hint.
// __launch_bounds__(256,3) pins 3 waves/SIMD (r6/r7 config).  Fixed-shift
// softmax (exact), mask folded into exp bias.  P strip padded to 72.
// P stored key-permuted (pos=lr*4+j); vhT carries the same perm.
// Double-buffered K/V via glds, 1 barrier/tile.  LDS 50KB.
// ---------------------------------------------------------------------------
__global__ __launch_bounds__(256, 3) void attn_kernel(const bf16* __restrict__ qh,
                                                      const bf16* __restrict__ kh,
                                                      const bf16* __restrict__ vhT,
                                                      const float* __restrict__ wts,
                                                      bf16* __restrict__ att)
{
    constexpr int LDP = 72;
    __shared__ bf16 Ks[2][64 * 64];
    __shared__ bf16 Vs[2][64 * 64];
    __shared__ bf16 Plds[4][32 * LDP];

    const int tid  = threadIdx.x;
    const int lane = tid & 63;
    const int wave = tid >> 6;
    const int lr   = lane & 15;
    const int q    = lane >> 4;
    const int bh   = blockIdx.x;               // 0..63
    const int bb   = bh >> 4;
    const int h    = bh & 15;
    const int q0w  = blockIdx.y * 128 + wave * 32;
    const size_t base = (size_t)bh * 1024 * 64;

    const int cA = wave * 128 + lane;
    const int cB = cA + 64;
    const int rowA = cA >> 3, gA = ((cA & 7) ^ (rowA & 7)) * 8;
    const int rowB = cB >> 3, gB = ((cB & 7) ^ (rowB & 7)) * 8;

    frag aq[2][2];
    #pragma unroll
    for (int rf = 0; rf < 2; rf++)
        #pragma unroll
        for (int ks = 0; ks < 2; ks++)
            aq[rf][ks] = *(const frag*)(&qh[base + (size_t)(q0w + rf * 16 + lr) * 64 + ks * 32 + q * 8]);

    float rs[2][4];
    f4 o[2][4];
    #pragma unroll
    for (int rf = 0; rf < 2; rf++)
        #pragma unroll
        for (int j = 0; j < 4; j++) {
            o[rf][j] = f4{0.f, 0.f, 0.f, 0.f};
            rs[rf][j] = 0.f;
        }

    gl2lds16(&kh [base + (size_t)rowA * 64 + gA],   &Ks[0][wave * 1024]);
    gl2lds16(&kh [base + (size_t)rowB * 64 + gB],   &Ks[0][wave * 1024 + 512]);
    gl2lds16(&vhT[base + (size_t)rowA * 1024 + gA], &Vs[0][wave * 1024]);
    gl2lds16(&vhT[base + (size_t)rowB * 1024 + gB], &Vs[0][wave * 1024 + 512]);
    __syncthreads();

    for (int t = 0; t < 16; t++) {
        const int k0  = t * 64;
        const int buf = t & 1;
        if (t < 15) {
            int kn = k0 + 64;
            gl2lds16(&kh [base + (size_t)(kn + rowA) * 64 + gA],  &Ks[buf ^ 1][wave * 1024]);
            gl2lds16(&kh [base + (size_t)(kn + rowB) * 64 + gB],  &Ks[buf ^ 1][wave * 1024 + 512]);
            gl2lds16(&vhT[base + (size_t)rowA * 1024 + kn + gA], &Vs[buf ^ 1][wave * 1024]);
            gl2lds16(&vhT[base + (size_t)rowB * 1024 + kn + gB], &Vs[buf ^ 1][wave * 1024 + 512]);
        }

        // per-key scale; mask folded into bias (exp2(-1e30)=0)
        float sc2[4], eb[4];
        #pragma unroll
        for (int j = 0; j < 4; j++) {
            float w = wts[bb * 1024 + k0 + j * 16 + lr];
            sc2[j] = SC2K * w * w;
            eb[j]  = (w < WEPS) ? -1e30f : EBIAS;
        }

        // K fragments (shared across both row-groups)
        frag kb[4][2];
        #pragma unroll
        for (int j = 0; j < 4; j++) {
            int rowj = j * 16 + lr;
            kb[j][0] = *(const frag*)(&Ks[buf][rowj * 64 + (((q    ) ^ (rowj & 7)) * 8)]);
            kb[j][1] = *(const frag*)(&Ks[buf][rowj * 64 + (((q + 4) ^ (rowj & 7)) * 8)]);
        }

        // S = Q K^T for both 16-row groups
        #pragma unroll
        for (int rf = 0; rf < 2; rf++) {
            f4 s[4];
            __builtin_amdgcn_s_setprio(1);
            #pragma unroll
            for (int j = 0; j < 4; j++) {
                f4 z = f4{0.f, 0.f, 0.f, 0.f};
                s[j] = __builtin_amdgcn_mfma_f32_16x16x32_bf16(aq[rf][0], kb[j][0], z, 0, 0, 0);
                s[j] = __builtin_amdgcn_mfma_f32_16x16x32_bf16(aq[rf][1], kb[j][1], s[j], 0, 0, 0);
            }
            __builtin_amdgcn_s_setprio(0);
            float p[4][4];
            #pragma unroll
            for (int j = 0; j < 4; j++)
                #pragma unroll
                for (int r = 0; r < 4; r++) {
                    p[j][r] = __builtin_amdgcn_exp2f(fmaf(s[j][r], sc2[j], eb[j]));
                    rs[rf][r] += p[j][r];
                }
            #pragma unroll
            for (int r = 0; r < 4; r++)
                *(uint2*)(&Plds[wave][(rf * 16 + q * 4 + r) * LDP + lr * 4]) =
                    pack4(p[0][r], p[1][r], p[2][r], p[3][r]);
        }

        // V fragments (shared across both row-groups)
        frag vb[4][2];
        #pragma unroll
        for (int j = 0; j < 4; j++) {
            int rowj = j * 16 + lr;
            vb[j][0] = *(const frag*)(&Vs[buf][rowj * 64 + (((q    ) ^ (rowj & 7)) * 8)]);
            vb[j][1] = *(const frag*)(&Vs[buf][rowj * 64 + (((q + 4) ^ (rowj & 7)) * 8)]);
        }

        #pragma unroll
        for (int rf = 0; rf < 2; rf++) {
            frag ap0 = *(const frag*)(&Plds[wave][(rf * 16 + lr) * LDP + q * 8]);
            frag ap1 = *(const frag*)(&Plds[wave][(rf * 16 + lr) * LDP + 32 + q * 8]);
            __builtin_amdgcn_s_setprio(1);
            #pragma unroll
            for (int j = 0; j < 4; j++) {
                o[rf][j] = __builtin_amdgcn_mfma_f32_16x16x32_bf16(ap0, vb[j][0], o[rf][j], 0, 0, 0);
                o[rf][j] = __builtin_amdgcn_mfma_f32_16x16x32_bf16(ap1, vb[j][1], o[rf][j], 0, 0, 0);
            }
            __builtin_amdgcn_s_setprio(0);
        }
        __syncthreads();
    }

    #pragma unroll
    for (int off = 1; off < 16; off <<= 1)
        #pragma unroll
        for (int rf = 0; rf < 2; rf++)
            #pragma unroll
            for (int r = 0; r < 4; r++)
                rs[rf][r] += __shfl_xor(rs[rf][r], off, 64);

    #pragma unroll
    for (int rf = 0; rf < 2; rf++) {
        float inv[4];
        #pragma unroll
        for (int r = 0; r < 4; r++) inv[r] = 1.0f / rs[rf][r];
        const int t0 = q0w + rf * 16 + q * 4;
        #pragma unroll
        for (int j = 0; j < 4; j++) {
            int d = h * 64 + j * 16 + lr;
            #pragma unroll
            for (int r = 0; r < 4; r++)
                att[((size_t)bb * 1024 + t0 + r) * 1024 + d] =
                    __float2bfloat16(o[rf][j][r] * inv[r]);
        }
    }
}

// ---------------------------------------------------------------------------
extern "C" void kernel_launch(void* const* d_in, const int* in_sizes, int n_in,
                              void* d_out, int out_size, void* d_ws, size_t ws_size,
                              hipStream_t stream)
{
    const float* q   = (const float*)d_in[0];
    const float* k   = (const float*)d_in[1];
    const float* v   = (const float*)d_in[2];
    const float* wts = (const float*)d_in[3];
    const float* Wq  = (const float*)d_in[4];
    const float* bq  = (const float*)d_in[5];
    const float* Wk  = (const float*)d_in[6];
    const float* bk  = (const float*)d_in[7];
    const float* Wv  = (const float*)d_in[8];
    const float* bv  = (const float*)d_in[9];
    const float* Wo  = (const float*)d_in[10];
    const float* bo  = (const float*)d_in[11];
    float* out = (float*)d_out;

    const long long Mi = 1024 * 1024;
    bf16* qh  = (bf16*)d_ws;
    bf16* kh  = qh  + 4 * Mi;
    bf16* vhT = kh  + 4 * Mi;
    bf16* att = vhT + 4 * Mi;
    bf16* cvt = att + 4 * Mi;
    const size_t base_bytes = (size_t)32 * Mi;

    dim3 blk(256);

    if (ws_size >= base_bytes + (size_t)32 * Mi) {
        // FULL: pre-convert q,k,v + all weights to bf16
        CvtArgs ca{};
        ca.src[0] = q;  ca.src[1] = k;  ca.src[2] = v;
        ca.src[3] = Wq; ca.src[4] = Wk; ca.src[5] = Wv; ca.src[6] = Wo;
        long long bnd[8] = {0, 4*Mi, 8*Mi, 12*Mi, 13*Mi, 14*Mi, 15*Mi, 16*Mi};
        for (int i = 0; i < 8; i++) ca.bounds[i] = bnd[i];
        ca.total = 16 * Mi;
        cvt_kernel<<<8192, blk, 0, stream>>>(ca, cvt);

        GemmBatch gq{};
        gq.A[0] = cvt;          gq.A[1] = cvt + 4*Mi;   gq.A[2] = cvt + 14*Mi; // z2: A=Wv (swapped)
        gq.W[0] = cvt + 12*Mi;  gq.W[1] = cvt + 13*Mi;  gq.W[2] = cvt + 8*Mi;  // z2: W=v
        gq.bias[0] = bq; gq.bias[1] = bk; gq.bias[2] = bv;
        gq.Out[0] = qh;  gq.Out[1] = kh;  gq.Out[2] = vhT;
        gq.mode[0] = 0;  gq.mode[1] = 0;  gq.mode[2] = 4;
        gemm_batch<true, true><<<dim3(8, 32, 3), blk, 0, stream>>>(gq);

        attn_kernel<<<dim3(64, 8), blk, 0, stream>>>(qh, kh, vhT, wts, att);

        gemm_out<true><<<dim3(8, 64), blk, 0, stream>>>(att, cvt + 15*Mi, bo, out);
    } else if (ws_size >= base_bytes + (size_t)8 * Mi) {
        // HYBRID: pre-convert weights only
        CvtArgs ca{};
        ca.src[0] = Wq; ca.src[1] = Wk; ca.src[2] = Wv; ca.src[3] = Wo;
        long long bnd[8] = {0, 1*Mi, 2*Mi, 3*Mi, 4*Mi, 4*Mi, 4*Mi, 4*Mi};
        for (int i = 0; i < 8; i++) ca.bounds[i] = bnd[i];
        ca.total = 4 * Mi;
        cvt_kernel<<<2048, blk, 0, stream>>>(ca, cvt);

        GemmBatch gq{};
        gq.A[0] = q; gq.A[1] = k; gq.A[2] = v;
        gq.W[0] = cvt; gq.W[1] = cvt + 1*Mi; gq.W[2] = cvt + 2*Mi;
        gq.bias[0] = bq; gq.bias[1] = bk; gq.bias[2] = bv;
        gq.Out[0] = qh;  gq.Out[1] = kh;  gq.Out[2] = vhT;
        gq.mode[0] = 0;  gq.mode[1] = 0;  gq.mode[2] = 2;
        gemm_batch<false, true><<<dim3(8, 32, 3), blk, 0, stream>>>(gq);

        attn_kernel<<<dim3(64, 8), blk, 0, stream>>>(qh, kh, vhT, wts, att);

        gemm_out<true><<<dim3(8, 64), blk, 0, stream>>>(att, cvt + 3*Mi, bo, out);
    } else {
        // FALLBACK: no conversions
        GemmBatch gq{};
        gq.A[0] = q; gq.A[1] = k; gq.A[2] = v;
        gq.W[0] = Wq; gq.W[1] = Wk; gq.W[2] = Wv;
        gq.bias[0] = bq; gq.bias[1] = bk; gq.bias[2] = bv;
        gq.Out[0] = qh;  gq.Out[1] = kh;  gq.Out[2] = vhT;
        gq.mode[0] = 0;  gq.mode[1] = 0;  gq.mode[2] = 2;
        gemm_batch<false, false><<<dim3(8, 32, 3), blk, 0, stream>>>(gq);

        attn_kernel<<<dim3(64, 8), blk, 0, stream>>>(qh, kh, vhT, wts, att);

        gemm_out<false><<<dim3(8, 64), blk, 0, stream>>>(att, Wo, bo, out);
    }
}